// Round 1
// baseline (223.000 us; speedup 1.0000x reference)
//
#include <hip/hip_runtime.h>
#include <cstdint>
#include <cstddef>

typedef unsigned short ushort_t;
typedef unsigned int uint_t;

typedef __bf16 bf16x8 __attribute__((ext_vector_type(8)));
typedef float floatx4 __attribute__((ext_vector_type(4)));

#define B_ 16
#define N1_ 4096
#define N2_ 1024
#define C1_ 128
#define C2_ 256
#define DIN_ 384
#define DOUT_ 256
#define M_ (B_ * N1_)  // 65536

// ---------------- helpers ----------------

__device__ __forceinline__ ushort_t f2bf(float f) {
  unsigned int u = __builtin_bit_cast(unsigned int, f);
  u = (u + 0x7fffu + ((u >> 16) & 1u)) >> 16;  // RNE
  return (ushort_t)u;
}

__device__ __forceinline__ void gload_lds16(const void* g, void* s) {
  __builtin_amdgcn_global_load_lds(
      (__attribute__((address_space(1))) void*)(void*)g,
      (__attribute__((address_space(3))) void*)s, 16, 0, 0);
}

__device__ __forceinline__ void ins3(float& d0, float& d1, float& d2,
                                     int& i0, int& i1, int& i2,
                                     float d, int p) {
  bool c0 = d < d0, c1 = d < d1, c2 = d < d2;
  d2 = c1 ? d1 : (c2 ? d : d2);
  i2 = c1 ? i1 : (c2 ? p : i2);
  d1 = c0 ? d0 : (c1 ? d : d1);
  i1 = c0 ? i0 : (c1 ? p : i1);
  d0 = c0 ? d : d0;
  i0 = c0 ? p : i0;
}

// ---------------- kernel P: weight transpose + bf16 convert ----------------

__global__ __launch_bounds__(256) void prep_kernel(
    const float* __restrict__ W1, const float* __restrict__ W2,
    ushort_t* __restrict__ W1t, ushort_t* __restrict__ W2t) {
  int tid = blockIdx.x * 256 + threadIdx.x;
  if (tid < DOUT_ * DIN_) {  // W1t[n][k] = bf16(W1[k][n]),  [256][384]
    int n = tid / DIN_;
    int k = tid - n * DIN_;
    W1t[tid] = f2bf(W1[(size_t)k * DOUT_ + n]);
  }
  if (tid < DOUT_ * DOUT_) {  // W2t[n][k] = bf16(W2[k][n]),  [256][256]
    int n = tid >> 8;
    int k = tid & 255;
    W2t[tid] = f2bf(W2[(size_t)k * DOUT_ + n]);
  }
}

// ---------------- kernel A: 3-NN + inverse-distance weights ----------------
// grid: B * (N1/64) blocks, 256 threads. 4 threads per query point.

__global__ __launch_bounds__(256) void knn_kernel(
    const float* __restrict__ xyz1, const float* __restrict__ xyz2,
    int* __restrict__ idx_out, float* __restrict__ w_out) {
  __shared__ float xs[N2_], ys[N2_], zs[N2_];
  int b = blockIdx.x >> 6;
  int n1base = (blockIdx.x & 63) << 6;
  const float* p2 = xyz2 + (size_t)b * N2_ * 3;
  for (int i = threadIdx.x; i < N2_; i += 256) {
    xs[i] = p2[i * 3 + 0];
    ys[i] = p2[i * 3 + 1];
    zs[i] = p2[i * 3 + 2];
  }
  __syncthreads();

  int g = threadIdx.x >> 2;
  int sub = threadIdx.x & 3;
  int row = b * N1_ + n1base + g;
  const float* p1 = xyz1 + (size_t)row * 3;
  float x1 = p1[0], y1 = p1[1], z1 = p1[2];

  float d0 = 3.0e38f, d1 = 3.0e38f, d2 = 3.0e38f;
  int i0 = 0, i1 = 0, i2 = 0;

  for (int t = 0; t < N2_ / 4; ++t) {
    int p = sub + 4 * t;  // 4 distinct LDS addrs per wave -> broadcast, no conflict
    float dx = x1 - xs[p];
    float dy = y1 - ys[p];
    float dz = z1 - zs[p];
    float d = dx * dx + dy * dy + dz * dz;
    ins3(d0, d1, d2, i0, i1, i2, d, p);
  }

  // butterfly merge across the 4 sub-lanes (lanes 4g..4g+3)
#pragma unroll
  for (int m = 1; m <= 2; m <<= 1) {
    float e0 = __shfl_xor(d0, m), e1 = __shfl_xor(d1, m), e2 = __shfl_xor(d2, m);
    int j0 = __shfl_xor(i0, m), j1 = __shfl_xor(i1, m), j2 = __shfl_xor(i2, m);
    ins3(d0, d1, d2, i0, i1, i2, e0, j0);
    ins3(d0, d1, d2, i0, i1, i2, e1, j1);
    ins3(d0, d1, d2, i0, i1, i2, e2, j2);
  }

  if (sub == 0) {
    float r0 = 1.0f / fmaxf(d0, 1e-10f);
    float r1 = 1.0f / fmaxf(d1, 1e-10f);
    float r2 = 1.0f / fmaxf(d2, 1e-10f);
    float s = 1.0f / (r0 + r1 + r2);
    int base = row * 3;
    idx_out[base + 0] = i0;
    idx_out[base + 1] = i1;
    idx_out[base + 2] = i2;
    w_out[base + 0] = r0 * s;
    w_out[base + 1] = r1 * s;
    w_out[base + 2] = r2 * s;
  }
}

// ---------------- kernel B: interpolate + concat -> bf16 A1 [M, 384] -------
// grid: M/4 blocks, 256 threads; one wave per output row.

__global__ __launch_bounds__(256) void build_kernel(
    const float* __restrict__ feat1, const float* __restrict__ feat2,
    const int* __restrict__ idx, const float* __restrict__ w,
    ushort_t* __restrict__ A1) {
  int wave = threadIdx.x >> 6;
  int lane = threadIdx.x & 63;
  int row = blockIdx.x * 4 + wave;
  int b = row >> 12;

  const int* ip = idx + (size_t)row * 3;
  const float* wp = w + (size_t)row * 3;
  int i0 = ip[0], i1 = ip[1], i2 = ip[2];
  float w0 = wp[0], w1 = wp[1], w2 = wp[2];

  const float4* f0 = (const float4*)(feat2 + ((size_t)b * N2_ + i0) * C2_);
  const float4* f1 = (const float4*)(feat2 + ((size_t)b * N2_ + i1) * C2_);
  const float4* f2 = (const float4*)(feat2 + ((size_t)b * N2_ + i2) * C2_);
  float4 a = f0[lane];
  float4 c = f1[lane];
  float4 d = f2[lane];
  float vx = w0 * a.x + w1 * c.x + w2 * d.x;
  float vy = w0 * a.y + w1 * c.y + w2 * d.y;
  float vz = w0 * a.z + w1 * c.z + w2 * d.z;
  float vw = w0 * a.w + w1 * c.w + w2 * d.w;

  ushort_t* orow = A1 + (size_t)row * DIN_;
  uint_t lo = (uint_t)f2bf(vx) | ((uint_t)f2bf(vy) << 16);
  uint_t hi = (uint_t)f2bf(vz) | ((uint_t)f2bf(vw) << 16);
  ((uint2*)orow)[lane] = make_uint2(lo, hi);  // cols 4*lane .. 4*lane+3

  const float2* g1 = (const float2*)(feat1 + (size_t)row * C1_);
  float2 t = g1[lane];
  uint_t pk = (uint_t)f2bf(t.x) | ((uint_t)f2bf(t.y) << 16);
  *(uint_t*)(orow + C2_ + lane * 2) = pk;  // cols 256 + 2*lane
}

// ---------------- GEMM: C = relu(A[M,K] * Bt[N,K]^T + bias) ----------------
// m97 structure: 128x128 tile, BK=32, global_load_lds x16, 16x16x32 bf16 MFMA
// grid: (M/128, N/128), 256 threads (4 waves, each computes 64x64).

template <int K, bool OUT_BF16>
__global__ __launch_bounds__(256) void gemm_kernel(
    const ushort_t* __restrict__ A, const ushort_t* __restrict__ Bt,
    const float* __restrict__ bias, void* __restrict__ out) {
  __shared__ ushort_t As[128 * 32];
  __shared__ ushort_t Bs[128 * 32];
  const int m0 = blockIdx.x * 128;
  const int n0 = blockIdx.y * 128;
  const int wave = threadIdx.x >> 6;
  const int lane = threadIdx.x & 63;
  const int wm = wave & 1;
  const int wn = wave >> 1;

  floatx4 acc[4][4];
#pragma unroll
  for (int i = 0; i < 4; ++i)
#pragma unroll
    for (int j = 0; j < 4; ++j) acc[i][j] = (floatx4)0.0f;

  // LDS element offsets for this lane's fragments
  const int a_off = (wm * 64 + (lane & 15)) * 32 + (lane >> 4) * 8;
  const int b_off = (wn * 64 + (lane & 15)) * 32 + (lane >> 4) * 8;

  for (int kt = 0; kt < K; kt += 32) {
    __syncthreads();  // previous tile's ds_reads done before overwrite
#pragma unroll
    for (int i = 0; i < 2; ++i) {
      int e = (wave * 2 + i) * 512 + lane * 8;  // tile element index
      int r = e >> 5, c = e & 31;
      gload_lds16(A + (size_t)(m0 + r) * K + kt + c, &As[e]);
      gload_lds16(Bt + (size_t)(n0 + r) * K + kt + c, &Bs[e]);
    }
    __syncthreads();  // compiler drains vmcnt(0) before s_barrier

    bf16x8 af[4], bfr[4];
#pragma unroll
    for (int i = 0; i < 4; ++i) af[i] = *(const bf16x8*)&As[a_off + i * 512];
#pragma unroll
    for (int j = 0; j < 4; ++j) bfr[j] = *(const bf16x8*)&Bs[b_off + j * 512];
#pragma unroll
    for (int i = 0; i < 4; ++i)
#pragma unroll
      for (int j = 0; j < 4; ++j)
        acc[i][j] =
            __builtin_amdgcn_mfma_f32_16x16x32_bf16(af[i], bfr[j], acc[i][j], 0, 0, 0);
  }

  // epilogue: C/D layout col=lane&15, row=(lane>>4)*4+r
#pragma unroll
  for (int j = 0; j < 4; ++j) {
    int col = n0 + wn * 64 + j * 16 + (lane & 15);
    float bv = bias[col];
#pragma unroll
    for (int i = 0; i < 4; ++i) {
      int rbase = m0 + wm * 64 + i * 16 + ((lane >> 4) << 2);
#pragma unroll
      for (int r = 0; r < 4; ++r) {
        float v = acc[i][j][r] + bv;
        v = v > 0.0f ? v : 0.0f;
        size_t off = (size_t)(rbase + r) * DOUT_ + col;
        if constexpr (OUT_BF16)
          ((ushort_t*)out)[off] = f2bf(v);
        else
          ((float*)out)[off] = v;
      }
    }
  }
}

// ---------------- workspace layout ----------------

constexpr size_t OFF_W1T = 0;                              // 256*384*2 = 196608
constexpr size_t OFF_W2T = OFF_W1T + 196608;               // 256*256*2 = 131072
constexpr size_t OFF_IDX = OFF_W2T + 131072;               // 65536*3*4 = 786432
constexpr size_t OFF_W = OFF_IDX + 786432;                 // 65536*3*4 = 786432
constexpr size_t OFF_A1 = OFF_W + 786432;                  // 65536*384*2 = 50331648
constexpr size_t OFF_H = OFF_A1 + 50331648;                // 65536*256*2 = 33554432
constexpr size_t WS_TOTAL = OFF_H + 33554432;              // ~85.8 MB

extern "C" void kernel_launch(void* const* d_in, const int* in_sizes, int n_in,
                              void* d_out, int out_size, void* d_ws, size_t ws_size,
                              hipStream_t stream) {
  const float* xyz1 = (const float*)d_in[0];
  const float* feat1 = (const float*)d_in[1];
  const float* xyz2 = (const float*)d_in[2];
  const float* feat2 = (const float*)d_in[3];
  const float* W1 = (const float*)d_in[4];
  const float* b1 = (const float*)d_in[5];
  const float* W2 = (const float*)d_in[6];
  const float* b2 = (const float*)d_in[7];

  if (ws_size < WS_TOTAL) return;  // fail cleanly rather than corrupt

  char* ws = (char*)d_ws;
  ushort_t* W1t = (ushort_t*)(ws + OFF_W1T);
  ushort_t* W2t = (ushort_t*)(ws + OFF_W2T);
  int* idx = (int*)(ws + OFF_IDX);
  float* w = (float*)(ws + OFF_W);
  ushort_t* A1 = (ushort_t*)(ws + OFF_A1);
  ushort_t* H = (ushort_t*)(ws + OFF_H);

  prep_kernel<<<384, 256, 0, stream>>>(W1, W2, W1t, W2t);
  knn_kernel<<<B_ * (N1_ / 64), 256, 0, stream>>>(xyz1, xyz2, idx, w);
  build_kernel<<<M_ / 4, 256, 0, stream>>>(feat1, feat2, idx, w, A1);
  gemm_kernel<DIN_, true>
      <<<dim3(M_ / 128, DOUT_ / 128), 256, 0, stream>>>(A1, W1t, b1, H);
  gemm_kernel<DOUT_, false>
      <<<dim3(M_ / 128, DOUT_ / 128), 256, 0, stream>>>(H, W2t, b2, (float*)d_out);
}

// Round 2
// 217.354 us; speedup vs baseline: 1.0260x; 1.0260x over previous
//
#include <hip/hip_runtime.h>
#include <cstdint>
#include <cstddef>

typedef unsigned short ushort_t;
typedef unsigned int uint_t;

typedef __bf16 bf16x8 __attribute__((ext_vector_type(8)));
typedef float floatx4 __attribute__((ext_vector_type(4)));

#define B_ 16
#define N1_ 4096
#define N2_ 1024
#define C1_ 128
#define C2_ 256
#define DIN_ 384
#define DOUT_ 256
#define M_ (B_ * N1_)  // 65536

// ---------------- helpers ----------------

__device__ __forceinline__ ushort_t f2bf(float f) {
  unsigned int u = __builtin_bit_cast(unsigned int, f);
  u = (u + 0x7fffu + ((u >> 16) & 1u)) >> 16;  // RNE
  return (ushort_t)u;
}

__device__ __forceinline__ void gload_lds16(const void* g, void* s) {
  __builtin_amdgcn_global_load_lds(
      (__attribute__((address_space(1))) void*)(void*)g,
      (__attribute__((address_space(3))) void*)s, 16, 0, 0);
}

// ---------------- kernel P: weight transpose + bf16 convert ----------------

__global__ __launch_bounds__(256) void prep_kernel(
    const float* __restrict__ W1, const float* __restrict__ W2,
    ushort_t* __restrict__ W1t, ushort_t* __restrict__ W2t) {
  int tid = blockIdx.x * 256 + threadIdx.x;
  if (tid < DOUT_ * DIN_) {  // W1t[n][k] = bf16(W1[k][n]),  [256][384]
    int n = tid / DIN_;
    int k = tid - n * DIN_;
    W1t[tid] = f2bf(W1[(size_t)k * DOUT_ + n]);
  }
  if (tid < DOUT_ * DOUT_) {  // W2t[n][k] = bf16(W2[k][n]),  [256][256]
    int n = tid >> 8;
    int k = tid & 255;
    W2t[tid] = f2bf(W2[(size_t)k * DOUT_ + n]);
  }
}

// ---------------- kernel A: 3-NN + inverse-distance weights ----------------
// grid: B * (N1/32) = 2048 blocks, 256 threads. 8 threads per query point,
// 32 queries per block. xyz2 staged as float4 in LDS (one ds_read_b128/eval).

__device__ __forceinline__ void ins_exact(float& s0, float& s1, float& s2,
                                          int& i0, int& i1, int& i2,
                                          float d, int p) {
  // values: exact sorted-insert via min/med3 (3 ops)
  float ns2 = __builtin_amdgcn_fmed3f(d, s1, s2);
  float ns1 = __builtin_amdgcn_fmed3f(d, s0, s1);
  float ns0 = fminf(d, s0);
  // indices: strict < keeps earlier candidate (scan order is ascending p)
  bool c0 = d < s0, c1 = d < s1, c2 = d < s2;
  i2 = c1 ? i1 : (c2 ? p : i2);
  i1 = c0 ? i0 : (c1 ? p : i1);
  i0 = c0 ? p : i0;
  s0 = ns0; s1 = ns1; s2 = ns2;
}

__device__ __forceinline__ void ins_merge(float& s0, float& s1, float& s2,
                                          int& i0, int& i1, int& i2,
                                          float e, int j) {
  // tie-break on smaller index (matches numpy first-occurrence top_k)
  bool t0 = (e < s0) || (e == s0 && j < i0);
  bool t1 = (e < s1) || (e == s1 && j < i1);
  bool t2 = (e < s2) || (e == s2 && j < i2);
  s2 = t1 ? s1 : (t2 ? e : s2);
  i2 = t1 ? i1 : (t2 ? j : i2);
  s1 = t0 ? s0 : (t1 ? e : s1);
  i1 = t0 ? i0 : (t1 ? j : i1);
  s0 = t0 ? e : s0;
  i0 = t0 ? j : i0;
}

__global__ __launch_bounds__(256) void knn_kernel(
    const float* __restrict__ xyz1, const float* __restrict__ xyz2,
    int* __restrict__ idx_out, float* __restrict__ w_out) {
  __shared__ float4 xs4[N2_];  // 16 KB
  int b = blockIdx.x >> 7;
  int n1base = (blockIdx.x & 127) << 5;  // 32 queries per block
  const float* p2 = xyz2 + (size_t)b * N2_ * 3;
  for (int i = threadIdx.x; i < N2_; i += 256) {
    const float* s = p2 + 3 * i;
    xs4[i] = make_float4(s[0], s[1], s[2], 0.0f);
  }
  __syncthreads();

  int g = threadIdx.x >> 3;   // query within block (0..31)
  int sub = threadIdx.x & 7;  // sub-thread (0..7)
  int row = b * N1_ + n1base + g;
  const float* p1 = xyz1 + (size_t)row * 3;
  float x1 = p1[0], y1 = p1[1], z1 = p1[2];

  float s0 = 3.0e38f, s1 = 3.0e38f, s2 = 3.0e38f;
  int i0 = 0, i1 = 0, i2 = 0;

  int p = sub;
#pragma unroll 8
  for (int t = 0; t < N2_ / 8; ++t) {
    float4 q = xs4[p];  // 8 distinct addrs/wave -> 32 banks, broadcast, clean
    float dx = x1 - q.x;
    float dy = y1 - q.y;
    float dz = z1 - q.z;
    float d = dx * dx + dy * dy + dz * dz;
    ins_exact(s0, s1, s2, i0, i1, i2, d, p);
    p += 8;
  }

  // butterfly merge across the 8 sub-lanes
#pragma unroll
  for (int m = 1; m <= 4; m <<= 1) {
    float e0 = __shfl_xor(s0, m), e1 = __shfl_xor(s1, m), e2 = __shfl_xor(s2, m);
    int j0 = __shfl_xor(i0, m), j1 = __shfl_xor(i1, m), j2 = __shfl_xor(i2, m);
    ins_merge(s0, s1, s2, i0, i1, i2, e0, j0);
    ins_merge(s0, s1, s2, i0, i1, i2, e1, j1);
    ins_merge(s0, s1, s2, i0, i1, i2, e2, j2);
  }

  if (sub == 0) {
    float r0 = 1.0f / fmaxf(s0, 1e-10f);
    float r1 = 1.0f / fmaxf(s1, 1e-10f);
    float r2 = 1.0f / fmaxf(s2, 1e-10f);
    float s = 1.0f / (r0 + r1 + r2);
    int base = row * 3;
    idx_out[base + 0] = i0;
    idx_out[base + 1] = i1;
    idx_out[base + 2] = i2;
    w_out[base + 0] = r0 * s;
    w_out[base + 1] = r1 * s;
    w_out[base + 2] = r2 * s;
  }
}

// ---------------- kernel B: interpolate + concat -> bf16 A1 [M, 384] -------
// grid: M/4 blocks, 256 threads; one wave per output row.

__global__ __launch_bounds__(256) void build_kernel(
    const float* __restrict__ feat1, const float* __restrict__ feat2,
    const int* __restrict__ idx, const float* __restrict__ w,
    ushort_t* __restrict__ A1) {
  int wave = threadIdx.x >> 6;
  int lane = threadIdx.x & 63;
  int row = blockIdx.x * 4 + wave;
  int b = row >> 12;

  const int* ip = idx + (size_t)row * 3;
  const float* wp = w + (size_t)row * 3;
  int i0 = ip[0], i1 = ip[1], i2 = ip[2];
  float w0 = wp[0], w1 = wp[1], w2 = wp[2];

  const float4* f0 = (const float4*)(feat2 + ((size_t)b * N2_ + i0) * C2_);
  const float4* f1 = (const float4*)(feat2 + ((size_t)b * N2_ + i1) * C2_);
  const float4* f2 = (const float4*)(feat2 + ((size_t)b * N2_ + i2) * C2_);
  float4 a = f0[lane];
  float4 c = f1[lane];
  float4 d = f2[lane];
  float vx = w0 * a.x + w1 * c.x + w2 * d.x;
  float vy = w0 * a.y + w1 * c.y + w2 * d.y;
  float vz = w0 * a.z + w1 * c.z + w2 * d.z;
  float vw = w0 * a.w + w1 * c.w + w2 * d.w;

  ushort_t* orow = A1 + (size_t)row * DIN_;
  uint_t lo = (uint_t)f2bf(vx) | ((uint_t)f2bf(vy) << 16);
  uint_t hi = (uint_t)f2bf(vz) | ((uint_t)f2bf(vw) << 16);
  ((uint2*)orow)[lane] = make_uint2(lo, hi);  // cols 4*lane .. 4*lane+3

  const float2* g1 = (const float2*)(feat1 + (size_t)row * C1_);
  float2 t = g1[lane];
  uint_t pk = (uint_t)f2bf(t.x) | ((uint_t)f2bf(t.y) << 16);
  *(uint_t*)(orow + C2_ + lane * 2) = pk;  // cols 256 + 2*lane
}

// ---------------- GEMM: C = relu(A[M,K] * Bt[N,K]^T + bias) ----------------
// 128x256 tile (full N in one block), BK=32, global_load_lds x16,
// 16x16x32 bf16 MFMA. grid: M/128 = 512 blocks (exactly 2/CU), 256 threads
// (4 waves, each computes 64x128 = 4x8 frags).

template <int K, bool OUT_BF16>
__global__ __launch_bounds__(256, 2) void gemm_kernel(
    const ushort_t* __restrict__ A, const ushort_t* __restrict__ Bt,
    const float* __restrict__ bias, void* __restrict__ out) {
  __shared__ ushort_t As[128 * 32];  // 8 KB
  __shared__ ushort_t Bs[256 * 32];  // 16 KB
  const int m0 = blockIdx.x * 128;
  const int tid = threadIdx.x;
  const int wave = tid >> 6;
  const int lane = tid & 63;
  const int wm = wave & 1;   // m-half (64 rows)
  const int wn = wave >> 1;  // n-half (128 cols)

  floatx4 acc[4][8];
#pragma unroll
  for (int i = 0; i < 4; ++i)
#pragma unroll
    for (int j = 0; j < 8; ++j) acc[i][j] = (floatx4)0.0f;

  const int a_off = (wm * 64 + (lane & 15)) * 32 + (lane >> 4) * 8;
  const int b_off = (wn * 128 + (lane & 15)) * 32 + (lane >> 4) * 8;

  for (int kt = 0; kt < K; kt += 32) {
    __syncthreads();  // previous tile's ds_reads done before overwrite
#pragma unroll
    for (int i = 0; i < 2; ++i) {  // A tile: 128x32 = 4096 elems
      int e = (i * 256 + tid) * 8;
      int r = e >> 5, c = e & 31;
      gload_lds16(A + (size_t)(m0 + r) * K + kt + c, &As[e]);
    }
#pragma unroll
    for (int i = 0; i < 4; ++i) {  // B tile: 256x32 = 8192 elems
      int e = (i * 256 + tid) * 8;
      int r = e >> 5, c = e & 31;
      gload_lds16(Bt + (size_t)r * K + kt + c, &Bs[e]);
    }
    __syncthreads();  // compiler drains vmcnt(0) before s_barrier

    bf16x8 af[4], bfr[8];
#pragma unroll
    for (int i = 0; i < 4; ++i) af[i] = *(const bf16x8*)&As[a_off + i * 512];
#pragma unroll
    for (int j = 0; j < 8; ++j) bfr[j] = *(const bf16x8*)&Bs[b_off + j * 512];
#pragma unroll
    for (int i = 0; i < 4; ++i)
#pragma unroll
      for (int j = 0; j < 8; ++j)
        acc[i][j] =
            __builtin_amdgcn_mfma_f32_16x16x32_bf16(af[i], bfr[j], acc[i][j], 0, 0, 0);
  }

  // epilogue: C/D layout col=lane&15, row=(lane>>4)*4+r
#pragma unroll
  for (int j = 0; j < 8; ++j) {
    int col = wn * 128 + j * 16 + (lane & 15);
    float bv = bias[col];
#pragma unroll
    for (int i = 0; i < 4; ++i) {
      int rbase = m0 + wm * 64 + i * 16 + ((lane >> 4) << 2);
#pragma unroll
      for (int r = 0; r < 4; ++r) {
        float v = acc[i][j][r] + bv;
        v = v > 0.0f ? v : 0.0f;
        size_t off = (size_t)(rbase + r) * DOUT_ + col;
        if constexpr (OUT_BF16)
          ((ushort_t*)out)[off] = f2bf(v);
        else
          ((float*)out)[off] = v;
      }
    }
  }
}

// ---------------- workspace layout ----------------

constexpr size_t OFF_W1T = 0;                              // 256*384*2 = 196608
constexpr size_t OFF_W2T = OFF_W1T + 196608;               // 256*256*2 = 131072
constexpr size_t OFF_IDX = OFF_W2T + 131072;               // 65536*3*4 = 786432
constexpr size_t OFF_W = OFF_IDX + 786432;                 // 65536*3*4 = 786432
constexpr size_t OFF_A1 = OFF_W + 786432;                  // 65536*384*2 = 50331648
constexpr size_t OFF_H = OFF_A1 + 50331648;                // 65536*256*2 = 33554432
constexpr size_t WS_TOTAL = OFF_H + 33554432;              // ~85.8 MB

extern "C" void kernel_launch(void* const* d_in, const int* in_sizes, int n_in,
                              void* d_out, int out_size, void* d_ws, size_t ws_size,
                              hipStream_t stream) {
  const float* xyz1 = (const float*)d_in[0];
  const float* feat1 = (const float*)d_in[1];
  const float* xyz2 = (const float*)d_in[2];
  const float* feat2 = (const float*)d_in[3];
  const float* W1 = (const float*)d_in[4];
  const float* b1 = (const float*)d_in[5];
  const float* W2 = (const float*)d_in[6];
  const float* b2 = (const float*)d_in[7];

  if (ws_size < WS_TOTAL) return;  // fail cleanly rather than corrupt

  char* ws = (char*)d_ws;
  ushort_t* W1t = (ushort_t*)(ws + OFF_W1T);
  ushort_t* W2t = (ushort_t*)(ws + OFF_W2T);
  int* idx = (int*)(ws + OFF_IDX);
  float* w = (float*)(ws + OFF_W);
  ushort_t* A1 = (ushort_t*)(ws + OFF_A1);
  ushort_t* H = (ushort_t*)(ws + OFF_H);

  prep_kernel<<<384, 256, 0, stream>>>(W1, W2, W1t, W2t);
  knn_kernel<<<B_ * (N1_ / 32), 256, 0, stream>>>(xyz1, xyz2, idx, w);
  build_kernel<<<M_ / 4, 256, 0, stream>>>(feat1, feat2, idx, w, A1);
  gemm_kernel<DIN_, true><<<M_ / 128, 256, 0, stream>>>(A1, W1t, b1, H);
  gemm_kernel<DOUT_, false><<<M_ / 128, 256, 0, stream>>>(H, W2t, b2, (float*)d_out);
}

// Round 3
// 191.614 us; speedup vs baseline: 1.1638x; 1.1343x over previous
//
#include <hip/hip_runtime.h>
#include <cstdint>
#include <cstddef>

typedef unsigned short ushort_t;
typedef unsigned int uint_t;

typedef __bf16 bf16x8 __attribute__((ext_vector_type(8)));
typedef float floatx4 __attribute__((ext_vector_type(4)));

#define B_ 16
#define N1_ 4096
#define N2_ 1024
#define C1_ 128
#define C2_ 256
#define DIN_ 384
#define DOUT_ 256
#define M_ (B_ * N1_)  // 65536

// ---------------- helpers ----------------

__device__ __forceinline__ ushort_t f2bf(float f) {
  unsigned int u = __builtin_bit_cast(unsigned int, f);
  u = (u + 0x7fffu + ((u >> 16) & 1u)) >> 16;  // RNE
  return (ushort_t)u;
}

// ---------------- kernel P: weight swizzle + bf16 convert ----------------
// W1s[t][n][kk] = bf16(W1[t*32+kk][n]), t=0..11, n=0..255, kk=0..31
// (exact B-fragment order: a wave's frag load = contiguous 1 KB)

__global__ __launch_bounds__(256) void prep_kernel(
    const float* __restrict__ W1, const float* __restrict__ W2,
    ushort_t* __restrict__ W1s, ushort_t* __restrict__ W2s) {
  int e = blockIdx.x * 256 + threadIdx.x;
  if (e < DOUT_ * DIN_) {  // 98304
    int kk = e & 31, n = (e >> 5) & 255, t = e >> 13;
    W1s[e] = f2bf(W1[(size_t)(t * 32 + kk) * DOUT_ + n]);
  }
  if (e < DOUT_ * DOUT_) {  // 65536
    int kk = e & 31, n = (e >> 5) & 255, t = e >> 13;
    W2s[e] = f2bf(W2[(size_t)(t * 32 + kk) * DOUT_ + n]);
  }
}

// ---------------- kernel A: 3-NN + inverse-distance weights ----------------
// (unchanged from round 2 — known-correct, VALU-bound at ~44 us)

__device__ __forceinline__ void ins_exact(float& s0, float& s1, float& s2,
                                          int& i0, int& i1, int& i2,
                                          float d, int p) {
  float ns2 = __builtin_amdgcn_fmed3f(d, s1, s2);
  float ns1 = __builtin_amdgcn_fmed3f(d, s0, s1);
  float ns0 = fminf(d, s0);
  bool c0 = d < s0, c1 = d < s1, c2 = d < s2;
  i2 = c1 ? i1 : (c2 ? p : i2);
  i1 = c0 ? i0 : (c1 ? p : i1);
  i0 = c0 ? p : i0;
  s0 = ns0; s1 = ns1; s2 = ns2;
}

__device__ __forceinline__ void ins_merge(float& s0, float& s1, float& s2,
                                          int& i0, int& i1, int& i2,
                                          float e, int j) {
  bool t0 = (e < s0) || (e == s0 && j < i0);
  bool t1 = (e < s1) || (e == s1 && j < i1);
  bool t2 = (e < s2) || (e == s2 && j < i2);
  s2 = t1 ? s1 : (t2 ? e : s2);
  i2 = t1 ? i1 : (t2 ? j : i2);
  s1 = t0 ? s0 : (t1 ? e : s1);
  i1 = t0 ? i0 : (t1 ? j : i1);
  s0 = t0 ? e : s0;
  i0 = t0 ? j : i0;
}

__global__ __launch_bounds__(256) void knn_kernel(
    const float* __restrict__ xyz1, const float* __restrict__ xyz2,
    int* __restrict__ idx_out, float* __restrict__ w_out) {
  __shared__ float4 xs4[N2_];  // 16 KB
  int b = blockIdx.x >> 7;
  int n1base = (blockIdx.x & 127) << 5;
  const float* p2 = xyz2 + (size_t)b * N2_ * 3;
  for (int i = threadIdx.x; i < N2_; i += 256) {
    const float* s = p2 + 3 * i;
    xs4[i] = make_float4(s[0], s[1], s[2], 0.0f);
  }
  __syncthreads();

  int g = threadIdx.x >> 3;
  int sub = threadIdx.x & 7;
  int row = b * N1_ + n1base + g;
  const float* p1 = xyz1 + (size_t)row * 3;
  float x1 = p1[0], y1 = p1[1], z1 = p1[2];

  float s0 = 3.0e38f, s1 = 3.0e38f, s2 = 3.0e38f;
  int i0 = 0, i1 = 0, i2 = 0;

  int p = sub;
#pragma unroll 8
  for (int t = 0; t < N2_ / 8; ++t) {
    float4 qv = xs4[p];
    float dx = x1 - qv.x;
    float dy = y1 - qv.y;
    float dz = z1 - qv.z;
    float d = dx * dx + dy * dy + dz * dz;
    ins_exact(s0, s1, s2, i0, i1, i2, d, p);
    p += 8;
  }

#pragma unroll
  for (int mm = 1; mm <= 4; mm <<= 1) {
    float e0 = __shfl_xor(s0, mm), e1 = __shfl_xor(s1, mm), e2 = __shfl_xor(s2, mm);
    int j0 = __shfl_xor(i0, mm), j1 = __shfl_xor(i1, mm), j2 = __shfl_xor(i2, mm);
    ins_merge(s0, s1, s2, i0, i1, i2, e0, j0);
    ins_merge(s0, s1, s2, i0, i1, i2, e1, j1);
    ins_merge(s0, s1, s2, i0, i1, i2, e2, j2);
  }

  if (sub == 0) {
    float r0 = 1.0f / fmaxf(s0, 1e-10f);
    float r1 = 1.0f / fmaxf(s1, 1e-10f);
    float r2 = 1.0f / fmaxf(s2, 1e-10f);
    float s = 1.0f / (r0 + r1 + r2);
    int base = row * 3;
    idx_out[base + 0] = i0;
    idx_out[base + 1] = i1;
    idx_out[base + 2] = i2;
    w_out[base + 0] = r0 * s;
    w_out[base + 1] = r1 * s;
    w_out[base + 2] = r2 * s;
  }
}

// ---------------- fused: build + GEMM1 + GEMM2 ----------------
// 64 rows/block, 1024 blocks, 256 threads (4 waves; wave w owns col-quarter
// [64w, 64w+64) of both GEMMs). A-tile lives only in LDS (m97 k-tiled
// layout). W b-frags are direct global loads from the pre-swizzled weight
// arrays (L2-hot, fully coalesced 1KB/frag), register double-buffered.
// NO barriers inside the K-loops. H lives only in LDS (XOR-chunk swizzle).

__global__ __launch_bounds__(256, 2) void fused_kernel(
    const float* __restrict__ feat1, const float* __restrict__ feat2,
    const int* __restrict__ idx, const float* __restrict__ w,
    const ushort_t* __restrict__ W1s, const float* __restrict__ b1,
    const ushort_t* __restrict__ W2s, const float* __restrict__ b2,
    float* __restrict__ out) {
  __shared__ ushort_t As[64 * 384];  // 48 KB; HS (64x256 = 32 KB) aliases front
  const int tid = threadIdx.x;
  const int wave = tid >> 6;
  const int lane = tid & 63;
  const int m = lane & 15;
  const int q = lane >> 4;
  const int row0 = blockIdx.x * 64;
  const int b = row0 >> 12;

  // ---- build phase: As[t][row][kk] (t = k/32), bf16 ----
#pragma unroll 4
  for (int it = 0; it < 16; ++it) {
    int rl = wave * 16 + it;
    int row = row0 + rl;
    const int* ip = idx + (size_t)row * 3;
    const float* wp = w + (size_t)row * 3;
    int i0 = ip[0], i1 = ip[1], i2 = ip[2];
    float w0 = wp[0], w1 = wp[1], w2 = wp[2];

    const float4* f0 = (const float4*)(feat2 + ((size_t)b * N2_ + i0) * C2_);
    const float4* f1 = (const float4*)(feat2 + ((size_t)b * N2_ + i1) * C2_);
    const float4* f2 = (const float4*)(feat2 + ((size_t)b * N2_ + i2) * C2_);
    float4 a = f0[lane];
    float4 c = f1[lane];
    float4 d = f2[lane];
    float vx = w0 * a.x + w1 * c.x + w2 * d.x;
    float vy = w0 * a.y + w1 * c.y + w2 * d.y;
    float vz = w0 * a.z + w1 * c.z + w2 * d.z;
    float vw = w0 * a.w + w1 * c.w + w2 * d.w;
    // cols 4*lane .. 4*lane+3 (never straddle a 32-col tile)
    uint_t lo = (uint_t)f2bf(vx) | ((uint_t)f2bf(vy) << 16);
    uint_t hi = (uint_t)f2bf(vz) | ((uint_t)f2bf(vw) << 16);
    int e = (lane >> 3) * 2048 + rl * 32 + ((4 * lane) & 31);
    *(uint2*)&As[e] = make_uint2(lo, hi);

    // feat1: cols 256 + 2*lane, 2*lane+1
    float2 t1 = ((const float2*)(feat1 + (size_t)row * C1_))[lane];
    uint_t pk = (uint_t)f2bf(t1.x) | ((uint_t)f2bf(t1.y) << 16);
    int e1 = (8 + (lane >> 4)) * 2048 + rl * 32 + ((2 * lane) & 31);
    *(uint_t*)&As[e1] = pk;
  }
  __syncthreads();

  // ---- GEMM1: acc[64 rows][64 cols per wave], K = 384, no barriers ----
  const int b_off = (wave * 64 + m) * 32 + q * 8;  // frag base in W1s/W2s tile
  const int a_base = m * 32 + q * 8;

  floatx4 acc[4][4];
#pragma unroll
  for (int i = 0; i < 4; ++i)
#pragma unroll
    for (int j = 0; j < 4; ++j) acc[i][j] = (floatx4)0.0f;

  {
    bf16x8 bf0[4], bf1[4], af[4];
#pragma unroll
    for (int j = 0; j < 4; ++j)
      bf0[j] = *(const bf16x8*)(W1s + b_off + j * 512);
#pragma unroll
    for (int t = 0; t < 12; t += 2) {
#pragma unroll
      for (int j = 0; j < 4; ++j)
        bf1[j] = *(const bf16x8*)(W1s + (size_t)(t + 1) * 8192 + b_off + j * 512);
#pragma unroll
      for (int i = 0; i < 4; ++i)
        af[i] = *(const bf16x8*)&As[t * 2048 + a_base + i * 512];
#pragma unroll
      for (int i = 0; i < 4; ++i)
#pragma unroll
        for (int j = 0; j < 4; ++j)
          acc[i][j] = __builtin_amdgcn_mfma_f32_16x16x32_bf16(af[i], bf0[j],
                                                              acc[i][j], 0, 0, 0);
      if (t + 2 < 12) {
#pragma unroll
        for (int j = 0; j < 4; ++j)
          bf0[j] = *(const bf16x8*)(W1s + (size_t)(t + 2) * 8192 + b_off + j * 512);
      }
#pragma unroll
      for (int i = 0; i < 4; ++i)
        af[i] = *(const bf16x8*)&As[(t + 1) * 2048 + a_base + i * 512];
#pragma unroll
      for (int i = 0; i < 4; ++i)
#pragma unroll
        for (int j = 0; j < 4; ++j)
          acc[i][j] = __builtin_amdgcn_mfma_f32_16x16x32_bf16(af[i], bf1[j],
                                                              acc[i][j], 0, 0, 0);
    }
  }
  __syncthreads();  // all As reads done before HS overwrites the region

  // ---- epilogue1: bias + relu -> bf16 HS (aliases As; XOR-chunk swizzle) ----
  ushort_t* HS = As;  // 64 x 256 = 16384 elems
#pragma unroll
  for (int j = 0; j < 4; ++j) {
    int col = wave * 64 + j * 16 + m;
    float bv = b1[col];
    int cb = (col >> 3) & 3;
    int tb = (col >> 5) * 2048 + (col & 7);
#pragma unroll
    for (int i = 0; i < 4; ++i)
#pragma unroll
      for (int r = 0; r < 4; ++r) {
        int row = i * 16 + q * 4 + r;
        float v = acc[i][j][r] + bv;
        v = v > 0.0f ? v : 0.0f;
        int ch = cb ^ ((row >> 2) & 3);
        HS[tb + row * 32 + ch * 8] = f2bf(v);
      }
  }
  __syncthreads();

  // ---- GEMM2: K = 256, a-frags from HS, no barriers ----
  floatx4 acc2[4][4];
#pragma unroll
  for (int i = 0; i < 4; ++i)
#pragma unroll
    for (int j = 0; j < 4; ++j) acc2[i][j] = (floatx4)0.0f;

  {
    bf16x8 bf0[4], bf1[4], af[4];
#pragma unroll
    for (int j = 0; j < 4; ++j)
      bf0[j] = *(const bf16x8*)(W2s + b_off + j * 512);
#pragma unroll
    for (int t = 0; t < 8; t += 2) {
#pragma unroll
      for (int j = 0; j < 4; ++j)
        bf1[j] = *(const bf16x8*)(W2s + (size_t)(t + 1) * 8192 + b_off + j * 512);
#pragma unroll
      for (int i = 0; i < 4; ++i) {
        int row = m + 16 * i;
        int ch = q ^ ((row >> 2) & 3);
        af[i] = *(const bf16x8*)&HS[t * 2048 + row * 32 + ch * 8];
      }
#pragma unroll
      for (int i = 0; i < 4; ++i)
#pragma unroll
        for (int j = 0; j < 4; ++j)
          acc2[i][j] = __builtin_amdgcn_mfma_f32_16x16x32_bf16(af[i], bf0[j],
                                                               acc2[i][j], 0, 0, 0);
      if (t + 2 < 8) {
#pragma unroll
        for (int j = 0; j < 4; ++j)
          bf0[j] = *(const bf16x8*)(W2s + (size_t)(t + 2) * 8192 + b_off + j * 512);
      }
#pragma unroll
      for (int i = 0; i < 4; ++i) {
        int row = m + 16 * i;
        int ch = q ^ ((row >> 2) & 3);
        af[i] = *(const bf16x8*)&HS[(t + 1) * 2048 + row * 32 + ch * 8];
      }
#pragma unroll
      for (int i = 0; i < 4; ++i)
#pragma unroll
        for (int j = 0; j < 4; ++j)
          acc2[i][j] = __builtin_amdgcn_mfma_f32_16x16x32_bf16(af[i], bf1[j],
                                                               acc2[i][j], 0, 0, 0);
    }
  }

  // ---- epilogue2: bias + relu -> fp32 out ----
#pragma unroll
  for (int j = 0; j < 4; ++j) {
    int col = wave * 64 + j * 16 + m;
    float bv = b2[col];
#pragma unroll
    for (int i = 0; i < 4; ++i)
#pragma unroll
      for (int r = 0; r < 4; ++r) {
        int row = i * 16 + q * 4 + r;
        float v = acc2[i][j][r] + bv;
        v = v > 0.0f ? v : 0.0f;
        out[(size_t)(row0 + row) * DOUT_ + col] = v;
      }
  }
}

// ---------------- workspace layout ----------------

constexpr size_t OFF_W1S = 0;                    // 256*384*2 = 196608
constexpr size_t OFF_W2S = OFF_W1S + 196608;     // 256*256*2 = 131072
constexpr size_t OFF_IDX = OFF_W2S + 131072;     // 65536*3*4 = 786432
constexpr size_t OFF_W = OFF_IDX + 786432;       // 65536*3*4 = 786432
constexpr size_t WS_TOTAL = OFF_W + 786432;      // ~1.9 MB

extern "C" void kernel_launch(void* const* d_in, const int* in_sizes, int n_in,
                              void* d_out, int out_size, void* d_ws, size_t ws_size,
                              hipStream_t stream) {
  const float* xyz1 = (const float*)d_in[0];
  const float* feat1 = (const float*)d_in[1];
  const float* xyz2 = (const float*)d_in[2];
  const float* feat2 = (const float*)d_in[3];
  const float* W1 = (const float*)d_in[4];
  const float* b1 = (const float*)d_in[5];
  const float* W2 = (const float*)d_in[6];
  const float* b2 = (const float*)d_in[7];

  if (ws_size < WS_TOTAL) return;

  char* ws = (char*)d_ws;
  ushort_t* W1s = (ushort_t*)(ws + OFF_W1S);
  ushort_t* W2s = (ushort_t*)(ws + OFF_W2S);
  int* idx = (int*)(ws + OFF_IDX);
  float* w = (float*)(ws + OFF_W);

  prep_kernel<<<384, 256, 0, stream>>>(W1, W2, W1s, W2s);
  knn_kernel<<<B_ * (N1_ / 32), 256, 0, stream>>>(xyz1, xyz2, idx, w);
  fused_kernel<<<M_ / 64, 256, 0, stream>>>(feat1, feat2, idx, w, W1s, b1, W2s,
                                            b2, (float*)d_out);
}